// Round 4
// baseline (425.723 us; speedup 1.0000x reference)
//
#include <hip/hip_runtime.h>
#include <math.h>

// SioConvLayer fused forward, MI355X (r4): planar complex output fix.
// Key identity: the L x L masked attention == complex linear recurrence
//   S_l = exp(ln_a_l) * S_{l-1} + kp_l (outer) v_l,  S_{-1} = hidden * exp(i*p_angle)
//   h_l = qp_l @ S_l
//   hidden_next = exp(i*p_angle*(L-1)) * S_{L-1}
// implemented as a 16-way chunked scan (chunk=64).
// GEMMs: f32 emulated as bf16 hi/lo split (3 MFMAs: hh + hl + lh; err ~2^-18 rel).
// r3 result: y PASSED (validates GEMMs, scan, attn, GN); hidden_next failed with
// error ~= 2.5x max|ref| => interleaved (re,im) layout was wrong. r4: planar
// real-plane + imag-plane write, imag plane guarded by out_size.

#define LSEQ 1024
#define NCHUNK 16
#define CHK 64

typedef float2 cf;
typedef unsigned short u16;
typedef unsigned int u32;
typedef __bf16 b16x8 __attribute__((ext_vector_type(8)));
typedef float f32x4 __attribute__((ext_vector_type(4)));

__device__ __forceinline__ cf cmul(cf a, cf b){
  return make_float2(a.x*b.x - a.y*b.y, a.x*b.y + a.y*b.x);
}
__device__ __forceinline__ cf cfma(cf a, cf b, cf c){
  c.x = fmaf(a.x, b.x, fmaf(-a.y, b.y, c.x));
  c.y = fmaf(a.x, b.y, fmaf( a.y, b.x, c.y));
  return c;
}
__device__ __forceinline__ cf cexpf2(cf a){
  float e = expf(a.x); float s, c; sincosf(a.y, &s, &c);
  return make_float2(e*c, e*s);
}
__device__ __forceinline__ float p_angle_f(int h, int i){
  // 1e-4 ** ((h*64+i)/512)
  return expf(((float)(h*64+i)) * (1.0f/512.0f) * logf(1e-4f));
}

// ------------------- f32 -> bf16 hi/lo split (RNE both) ----------------------
__device__ __forceinline__ u16 bf16_rne(float f){
  u32 u = __float_as_uint(f);
  u += 0x7fffu + ((u >> 16) & 1u);
  return (u16)(u >> 16);
}
__device__ __forceinline__ void split_bf16(float f, u16& h, u16& l){
  u32 u = __float_as_uint(f);
  u32 r = (u + 0x7fffu + ((u >> 16) & 1u)) >> 16;
  h = (u16)r;
  float d = f - __uint_as_float(r << 16);
  l = bf16_rne(d);
}

// stage ROWS x 32 f32 tile -> hi/lo bf16 LDS tiles (pitch KP=40 u16 = 80B)
template<int ROWS>
__device__ __forceinline__ void stage_tile(const float* __restrict__ G, int ld,
                                           int r0, int k0,
                                           u16* Sh, u16* Sl, int tid){
  #pragma unroll
  for (int q = 0; q < ROWS/32; q++){
    int s = tid + q*256;
    int row = s >> 3, kq = (s & 7) * 4;
    float4 v = *(const float4*)(G + (size_t)(r0+row)*ld + k0 + kq);
    u16 h0,h1,h2,h3,l0,l1,l2,l3;
    split_bf16(v.x, h0, l0);
    split_bf16(v.y, h1, l1);
    split_bf16(v.z, h2, l2);
    split_bf16(v.w, h3, l3);
    uint2 ph, pl;
    ph.x = (u32)h0 | ((u32)h1 << 16);  ph.y = (u32)h2 | ((u32)h3 << 16);
    pl.x = (u32)l0 | ((u32)l1 << 16);  pl.y = (u32)l2 | ((u32)l3 << 16);
    *(uint2*)&Sh[row*40 + kq] = ph;
    *(uint2*)&Sl[row*40 + kq] = pl;
  }
}

// ---------------- MFMA GEMM: C[m,n] = sum_k A[m,k]*B[n,k] + bias[n] ----------
// 256 threads = 4 waves in 2x2 grid; wave tile (BM/2)x(BN/2); 16x16x32 MFMA.
// A: [M][K] f32 row-major, B: [N][K] f32 row-major (both K-contiguous).
template<int BM, int BN>
__global__ __launch_bounds__(256, 2) void k_gemm_mfma(const float* __restrict__ A,
                                                      const float* __restrict__ B,
                                                      const float* __restrict__ bias,
                                                      float* __restrict__ C,
                                                      int M, int N, int K){
  constexpr int MI = BM/32, NJ = BN/32;   // 16x16 frags per wave
  constexpr int KP = 40;                  // u16 pitch: 80B -> conflict-free b128
  __shared__ u16 Ah[BM*KP], Al[BM*KP], Bh[BN*KP], Bl[BN*KP];
  int tid = threadIdx.x;
  int m0 = blockIdx.y * BM, n0 = blockIdx.x * BN;
  int wid = tid >> 6, lane = tid & 63;
  int wr = wid >> 1, wc = wid & 1;
  int fr = lane & 15, fq = lane >> 4;
  f32x4 acc[MI][NJ];
  #pragma unroll
  for (int mi = 0; mi < MI; mi++)
    #pragma unroll
    for (int nj = 0; nj < NJ; nj++)
      acc[mi][nj] = (f32x4){0.f, 0.f, 0.f, 0.f};

  for (int k0 = 0; k0 < K; k0 += 32){
    stage_tile<BM>(A, K, m0, k0, Ah, Al, tid);
    stage_tile<BN>(B, K, n0, k0, Bh, Bl, tid);
    __syncthreads();
    b16x8 a_h[MI], a_l[MI], b_h[NJ], b_l[NJ];
    #pragma unroll
    for (int mi = 0; mi < MI; mi++){
      int r = wr*(BM/2) + mi*16 + fr;
      a_h[mi] = *(const b16x8*)&Ah[r*KP + fq*8];
      a_l[mi] = *(const b16x8*)&Al[r*KP + fq*8];
    }
    #pragma unroll
    for (int nj = 0; nj < NJ; nj++){
      int r = wc*(BN/2) + nj*16 + fr;
      b_h[nj] = *(const b16x8*)&Bh[r*KP + fq*8];
      b_l[nj] = *(const b16x8*)&Bl[r*KP + fq*8];
    }
    #pragma unroll
    for (int mi = 0; mi < MI; mi++)
      #pragma unroll
      for (int nj = 0; nj < NJ; nj++){
        acc[mi][nj] = __builtin_amdgcn_mfma_f32_16x16x32_bf16(a_h[mi], b_h[nj], acc[mi][nj], 0, 0, 0);
        acc[mi][nj] = __builtin_amdgcn_mfma_f32_16x16x32_bf16(a_h[mi], b_l[nj], acc[mi][nj], 0, 0, 0);
        acc[mi][nj] = __builtin_amdgcn_mfma_f32_16x16x32_bf16(a_l[mi], b_h[nj], acc[mi][nj], 0, 0, 0);
      }
    __syncthreads();
  }
  // epilogue: C/D layout (m89-verified): col = lane&15, row = (lane>>4)*4 + reg
  #pragma unroll
  for (int mi = 0; mi < MI; mi++)
    #pragma unroll
    for (int nj = 0; nj < NJ; nj++){
      int n = n0 + wc*(BN/2) + nj*16 + fr;
      float bn = bias[n];
      #pragma unroll
      for (int r = 0; r < 4; r++){
        int m = m0 + wr*(BM/2) + mi*16 + fq*4 + r;
        C[(size_t)m*N + n] = acc[mi][nj][r] + bn;
      }
    }
}

// ---------------- small projections: a_angle, ln_a_abs, scale_qk -------------
__global__ __launch_bounds__(256) void k_small_proj(
    const float* __restrict__ x,
    const float* __restrict__ W_aang, const float* __restrict__ b_aang,
    const float* __restrict__ W_lnabs, const float* __restrict__ b_lnabs,
    const float* __restrict__ W_pscale, const float* __restrict__ b_pscale,
    float* __restrict__ lnA /*[BL][H][2]*/, float* __restrict__ scaleq /*[BL][H]*/){
  int bl = blockIdx.x;
  int tid = threadIdx.x;
  const float* xr = x + (size_t)bl*1024;
  float part[24];
  #pragma unroll
  for (int r = 0; r < 24; r++) part[r] = 0.f;
  for (int k = tid; k < 1024; k += 256){
    float xv = xr[k];
    #pragma unroll
    for (int h = 0; h < 8; h++){
      part[h]    = fmaf(xv, W_aang  [h*1024+k], part[h]);
      part[8+h]  = fmaf(xv, W_lnabs [h*1024+k], part[8+h]);
      part[16+h] = fmaf(xv, W_pscale[h*1024+k], part[16+h]);
    }
  }
  __shared__ float red[24][4];
  int lane = tid & 63, wv = tid >> 6;
  #pragma unroll
  for (int r = 0; r < 24; r++){
    float s = part[r];
    #pragma unroll
    for (int off = 32; off >= 1; off >>= 1) s += __shfl_down(s, off);
    if (lane == 0) red[r][wv] = s;
  }
  __syncthreads();
  if (tid < 24){
    red[tid][0] = red[tid][0] + red[tid][1] + red[tid][2] + red[tid][3];
  }
  __syncthreads();
  if (tid < 8){
    int h = tid;
    float aang  = tanhf(red[h][0] + b_aang[h]);
    float lnabs = -expf(red[8+h][0] + b_lnabs[h]);
    float scv   = red[16+h][0] + b_pscale[h];
    float sc    = -1.f / (1.f + expf(-scv));
    float pa0   = p_angle_f(h, 0);
    lnA[(bl*8+h)*2+0] = lnabs * pa0;
    lnA[(bl*8+h)*2+1] = aang  * pa0;
    scaleq[bl*8+h] = sc;
  }
}

// ---------------- inclusive cumsum of ln_a over L per (b,h) ------------------
__global__ void k_cumsum(const float* __restrict__ lnA, float* __restrict__ Aout /*[BH][L][2]*/){
  int bh = blockIdx.x; int b = bh >> 3, h = bh & 7;
  __shared__ float2 buf[2][LSEQ];
  int l = threadIdx.x;
  float2 v;
  v.x = lnA[(((size_t)b*LSEQ + l)*8 + h)*2 + 0];
  v.y = lnA[(((size_t)b*LSEQ + l)*8 + h)*2 + 1];
  buf[0][l] = v;
  __syncthreads();
  int src = 0;
  for (int off = 1; off < LSEQ; off <<= 1){
    float2 w = buf[src][l];
    if (l >= off){ float2 u = buf[src][l-off]; w.x += u.x; w.y += u.y; }
    buf[src^1][l] = w;
    __syncthreads();
    src ^= 1;
  }
  float2 r = buf[src][l];
  ((float2*)Aout)[(size_t)bh*LSEQ + l] = r;
}

// ---------------- t -> qp, kp, v ([BH][L][I] float2) -------------------------
__global__ __launch_bounds__(256) void k_transform(
    const float* __restrict__ t, const float* __restrict__ scaleq,
    float* __restrict__ qp, float* __restrict__ kp, float* __restrict__ v){
  int bl = blockIdx.x; int b = bl >> 10, l = bl & 1023;
  int tid = threadIdx.x;
  const float* tr = t + (size_t)bl*3072;
  float lnSc = logf(1024.f) - logf(32.f);
  for (int p = tid; p < 512; p += 256){
    int h = p >> 6, i = p & 63;
    const float2* tf = (const float2*)(tr + h*384 + i*6);
    float2 q  = tf[0];
    float2 kk = tf[1];
    float2 vv = tf[2];
    // z / (1 + |z|)
    float sq_ = 1.f/(1.f + sqrtf(q.x*q.x + q.y*q.y));   q.x*=sq_; q.y*=sq_;
    float sk_ = 1.f/(1.f + sqrtf(kk.x*kk.x + kk.y*kk.y)); kk.x*=sk_; kk.y*=sk_;
    float sv_ = 1.f/(1.f + sqrtf(vv.x*vv.x + vv.y*vv.y)); vv.x*=sv_; vv.y*=sv_;
    float pa  = p_angle_f(h, i);
    float pas = expf(logf(32.f) + ((float)h)*(1.f/7.f)*lnSc);
    float sc  = scaleq[bl*8+h];
    float diff = sc * pas * pa;
    float phase = pa * (float)l;
    float aq, ak;
    if ((i & 1) == 0){ aq = phase + diff; ak = -phase; }
    else             { aq = phase;        ak = -phase + diff; }
    float s1, c1; sincosf(aq, &s1, &c1);
    float s2, c2; sincosf(ak, &s2, &c2);
    float2 qpv = cmul(q,  make_float2(c1, s1));
    float2 kpv = cmul(kk, make_float2(c2, s2));
    size_t idx = (((size_t)(b*8+h))*LSEQ + l)*64 + i;
    ((float2*)qp)[idx] = qpv;
    ((float2*)kp)[idx] = kpv;
    ((float2*)v )[idx] = vv;
  }
}

// ---------------- per-chunk KV state T_c (stored transposed [j][i]) ----------
__global__ __launch_bounds__(256) void k_chunkT(
    const float* __restrict__ kp, const float* __restrict__ v,
    const float* __restrict__ A, float* __restrict__ T){
  int blk = blockIdx.x;            // bh*16 + c
  int bh = blk >> 4, c = blk & 15;
  int l0 = c*CHK;
  __shared__ float2 kpS[64][65];
  __shared__ float2 vS [64][65];
  __shared__ float2 wS [64];
  int tid = threadIdx.x;
  const float2* kpg = (const float2*)kp + ((size_t)bh*LSEQ + l0)*64;
  const float2* vg  = (const float2*)v  + ((size_t)bh*LSEQ + l0)*64;
  for (int e = tid; e < 4096; e += 256){
    kpS[e>>6][e&63] = kpg[e];
    vS [e>>6][e&63] = vg [e];
  }
  const float2* Ag = (const float2*)A + (size_t)bh*LSEQ;
  if (tid < 64){
    float2 Aend = Ag[l0+63];
    float2 Am   = Ag[l0+tid];
    wS[tid] = cexpf2(make_float2(Aend.x - Am.x, Aend.y - Am.y));
  }
  __syncthreads();
  int i = tid & 63, jg = tid >> 6;     // whole wave shares jg -> broadcast reads of vS
  float2 acc[16];
  #pragma unroll
  for (int jj = 0; jj < 16; jj++) acc[jj] = make_float2(0.f, 0.f);
  for (int m = 0; m < 64; m++){
    float2 wkp = cmul(wS[m], kpS[m][i]);
    #pragma unroll
    for (int jj = 0; jj < 16; jj++)
      acc[jj] = cfma(wkp, vS[m][jg*16+jj], acc[jj]);
  }
  float2* Tg = (float2*)T + (size_t)blk*4096;
  #pragma unroll
  for (int jj = 0; jj < 16; jj++)
    Tg[(jg*16+jj)*64 + i] = acc[jj];   // [j][i]: lanes over i -> coalesced
}

// ---------------- sequential chunk-state scan + hidden_next ------------------
// hidden_next written PLANAR: real plane [B,H,I,J] then imag plane (if room).
__global__ __launch_bounds__(256) void k_state_scan(
    const float* __restrict__ hidden_r, const float* __restrict__ hidden_i,
    const float* __restrict__ A, const float* __restrict__ T,
    float* __restrict__ S_states, float* __restrict__ out_re,
    float* __restrict__ out_im, int write_imag){
  int bh = blockIdx.x; int h = bh & 7;
  int tid = threadIdx.x;
  float2 S[16];
  #pragma unroll
  for (int t = 0; t < 16; t++){
    int e = tid + 256*t;           // e = j*64 + i (transposed layout)
    int j = e >> 6, i = e & 63;
    float pa = p_angle_f(h, i);
    float hr = hidden_r[(size_t)bh*4096 + i*64 + j];
    float hi = hidden_i[(size_t)bh*4096 + i*64 + j];
    float sn, cs; sincosf(pa, &sn, &cs);
    S[t] = cmul(make_float2(hr, hi), make_float2(cs, sn));
  }
  const float2* Ag = (const float2*)A + (size_t)bh*LSEQ;
  for (int c = 0; c < NCHUNK; c++){
    #pragma unroll
    for (int t = 0; t < 16; t++)
      ((float2*)S_states)[((size_t)bh*16 + c)*4096 + tid + 256*t] = S[t];
    float2 Aend  = Ag[c*CHK + 63];
    float2 Aprev = (c > 0) ? Ag[c*CHK - 1] : make_float2(0.f, 0.f);
    float2 P = cexpf2(make_float2(Aend.x - Aprev.x, Aend.y - Aprev.y));
    const float2* Tg = (const float2*)T + ((size_t)bh*16 + c)*4096;
    #pragma unroll
    for (int t = 0; t < 16; t++){
      float2 Tv = Tg[tid + 256*t];
      float2 Sn = cmul(P, S[t]);
      S[t] = make_float2(Sn.x + Tv.x, Sn.y + Tv.y);
    }
  }
  #pragma unroll
  for (int t = 0; t < 16; t++){
    int e = tid + 256*t;
    int j = e >> 6, i = e & 63;
    float pa = p_angle_f(h, i);
    float sn, cs; sincosf(pa * (float)(LSEQ-1), &sn, &cs);
    float2 r = cmul(S[t], make_float2(cs, sn));
    size_t o = (size_t)bh*4096 + i*64 + j;
    out_re[o] = r.x;
    if (write_imag) out_im[o] = r.y;
  }
}

// ---------------- per-chunk attention: intra-quadratic + cross-state ---------
__global__ __launch_bounds__(256) void k_attn(
    const float* __restrict__ qp, const float* __restrict__ kp,
    const float* __restrict__ v, const float* __restrict__ A,
    const float* __restrict__ S_states, float* __restrict__ hr_out){
  int blk = blockIdx.x;            // bh*16 + c
  int bh = blk >> 4, c = blk & 15;
  int b = bh >> 3, h = bh & 7;
  int l0 = c*CHK;
  __shared__ float2 bufQ[64][65];  // qp -> scaled qp -> v
  __shared__ float2 bufK[64][65];  // kp -> S^c ([j][i])
  __shared__ float2 bufC[64][65];  // qck
  __shared__ float2 dA[64];
  __shared__ float2 eD[64];
  int tid = threadIdx.x;
  const float2* qpg = (const float2*)qp + ((size_t)bh*LSEQ + l0)*64;
  const float2* kpg = (const float2*)kp + ((size_t)bh*LSEQ + l0)*64;
  for (int e = tid; e < 4096; e += 256){
    bufQ[e>>6][e&63] = qpg[e];
    bufK[e>>6][e&63] = kpg[e];
  }
  const float2* Ag = (const float2*)A + (size_t)bh*LSEQ;
  if (tid < 64){
    float2 As = (l0 > 0) ? Ag[l0-1] : make_float2(0.f, 0.f);
    float2 Al = Ag[l0+tid];
    float2 d = make_float2(Al.x - As.x, Al.y - As.y);
    dA[tid] = d;
    eD[tid] = cexpf2(d);
  }
  __syncthreads();

  // B1: qck[l][m] = exp(dA_l - dA_m) * (qp_l . kp_m), masked m<=l
  {
    int l = tid >> 2, mg = tid & 3;   // m = mg + 4*mm (bank-spread)
    float2 acc[16];
    #pragma unroll
    for (int mm = 0; mm < 16; mm++) acc[mm] = make_float2(0.f, 0.f);
    for (int i = 0; i < 64; i++){
      float2 qv = bufQ[l][i];
      #pragma unroll
      for (int mm = 0; mm < 16; mm++)
        acc[mm] = cfma(qv, bufK[mg + 4*mm][i], acc[mm]);
    }
    float2 dl = dA[l];
    #pragma unroll
    for (int mm = 0; mm < 16; mm++){
      int m = mg + 4*mm;
      float2 w = make_float2(0.f, 0.f);
      if (m <= l){
        float2 dm = dA[m];
        w = cexpf2(make_float2(dl.x - dm.x, dl.y - dm.y));
      }
      bufC[l][m] = cmul(acc[mm], w);
    }
  }
  __syncthreads();

  // scale qp rows by eD[l]; load S^c into bufK
  for (int e = tid; e < 4096; e += 256){
    int l = e >> 6, i = e & 63;
    bufQ[l][i] = cmul(bufQ[l][i], eD[l]);
  }
  const float2* Sg = (const float2*)S_states + (size_t)blk*4096;
  for (int e = tid; e < 4096; e += 256)
    bufK[e>>6][e&63] = Sg[e];        // bufK[j][i] = S[i][j]
  __syncthreads();

  // phase A: h_l[j] += sum_i qpw_l[i] * S[i][j]
  int l = tid >> 2, jg = tid & 3;    // j = jg + 4*jj
  float2 hacc[16];
  #pragma unroll
  for (int jj = 0; jj < 16; jj++) hacc[jj] = make_float2(0.f, 0.f);
  for (int i = 0; i < 64; i++){
    float2 qw = bufQ[l][i];
    #pragma unroll
    for (int jj = 0; jj < 16; jj++)
      hacc[jj] = cfma(qw, bufK[jg + 4*jj][i], hacc[jj]);
  }
  __syncthreads();
  // load v over bufQ
  const float2* vg = (const float2*)v + ((size_t)bh*LSEQ + l0)*64;
  for (int e = tid; e < 4096; e += 256)
    bufQ[e>>6][e&63] = vg[e];
  __syncthreads();
  // B2: h_l[j] += sum_m qck[l][m] * v_m[j]
  for (int m = 0; m < 64; m++){
    float2 qc = bufC[l][m];
    #pragma unroll
    for (int jj = 0; jj < 16; jj++)
      hacc[jj] = cfma(qc, bufQ[m][jg + 4*jj], hacc[jj]);
  }
  // write h as real layout [BL][H][2I] (pair (re,im) = float2 at channel j)
  float2* out = (float2*)hr_out;
  size_t base = (((size_t)(b*LSEQ + l0 + l))*8 + h)*64;
  #pragma unroll
  for (int jj = 0; jj < 16; jj++)
    out[base + jg + 4*jj] = hacc[jj];
}

// ---------------- GroupNorm (H groups of 128) * silu(g), in place ------------
__global__ __launch_bounds__(256) void k_gn(
    const float* __restrict__ g, float* __restrict__ hr,
    const float* __restrict__ gn_w, const float* __restrict__ gn_b){
  int bl = blockIdx.x;
  int tid = threadIdx.x;
  int h = tid >> 5, c32 = tid & 31;
  float* hp = hr + ((size_t)bl*8 + h)*128 + c32*4;
  const float* gp = g + (size_t)bl*1024 + h*128 + c32*4;
  float4 v = *(const float4*)hp;
  float s = v.x + v.y + v.z + v.w;
  #pragma unroll
  for (int off = 16; off >= 1; off >>= 1) s += __shfl_xor(s, off);
  float mean = s * (1.f/128.f);
  float dx = v.x - mean, dy = v.y - mean, dz = v.z - mean, dw = v.w - mean;
  float ss = dx*dx + dy*dy + dz*dz + dw*dw;
  #pragma unroll
  for (int off = 16; off >= 1; off >>= 1) ss += __shfl_xor(ss, off);
  float inv = rsqrtf(ss * (1.f/128.f) + 1e-5f);
  float w = gn_w[h] * inv, bb = gn_b[h];
  float4 gv = *(const float4*)gp;
  float4 o;
  o.x = (dx*w + bb) * (gv.x / (1.f + expf(-gv.x)));
  o.y = (dy*w + bb) * (gv.y / (1.f + expf(-gv.y)));
  o.z = (dz*w + bb) * (gv.z / (1.f + expf(-gv.z)));
  o.w = (dw*w + bb) * (gv.w / (1.f + expf(-gv.w)));
  *(float4*)hp = o;
}

extern "C" void kernel_launch(void* const* d_in, const int* in_sizes, int n_in,
                              void* d_out, int out_size, void* d_ws, size_t ws_size,
                              hipStream_t stream) {
  const float* x        = (const float*)d_in[0];
  const float* hidden_r = (const float*)d_in[1];
  const float* hidden_i = (const float*)d_in[2];
  const float* W_qkv    = (const float*)d_in[3];
  const float* b_qkv    = (const float*)d_in[4];
  const float* W_g      = (const float*)d_in[5];
  const float* b_g      = (const float*)d_in[6];
  const float* W_aang   = (const float*)d_in[7];
  const float* b_aang   = (const float*)d_in[8];
  const float* W_lnabs  = (const float*)d_in[9];
  const float* b_lnabs  = (const float*)d_in[10];
  const float* W_pscale = (const float*)d_in[11];
  const float* b_pscale = (const float*)d_in[12];
  const float* W_y      = (const float*)d_in[13];
  const float* b_y      = (const float*)d_in[14];
  const float* gn_w     = (const float*)d_in[15];
  const float* gn_b     = (const float*)d_in[16];

  float* ws = (float*)d_ws;
  // t_buf is 6,291,456 floats; after k_transform it is dead, so hr/T/S live inside it.
  float* t_buf  = ws;
  float* hr_buf = t_buf;                  // 2,097,152
  float* T_buf  = t_buf + 2097152;        // 2,097,152
  float* S_buf  = t_buf + 4194304;        // 2,097,152
  float* g_buf  = ws + 6291456;           // 2,097,152
  float* qp_buf = g_buf + 2097152;        // 2,097,152
  float* kp_buf = qp_buf + 2097152;       // 2,097,152
  float* v_buf  = kp_buf + 2097152;       // 2,097,152
  float* lnA    = v_buf + 2097152;        // 32,768
  float* scaleq = lnA + 32768;            // 16,384
  float* A_buf  = scaleq + 16384;         // 32,768
  // total: 14,761,984 floats = 59.0 MB

  float* y_out  = (float*)d_out;                 // 2,097,152 f32
  // hidden_next planar: real plane at +2,097,152 (65,536), imag plane after it
  // (only if the harness allocated room for it).
  float* hid_re = (float*)d_out + 2097152;
  float* hid_im = (float*)d_out + 2097152 + 65536;
  int write_imag = (out_size >= 2097152 + 2*65536) ? 1 : 0;

  // 1) t = x @ W_qkv^T + b_qkv    (M=2048, N=3072, K=1024) -> 384 blocks
  k_gemm_mfma<128,128><<<dim3(3072/128, 2048/128), 256, 0, stream>>>(x, W_qkv, b_qkv, t_buf, 2048, 3072, 1024);
  // 2) g = x @ W_g^T + b_g        (N=1024) -> 256 blocks
  k_gemm_mfma<64,128><<<dim3(1024/128, 2048/64), 256, 0, stream>>>(x, W_g, b_g, g_buf, 2048, 1024, 1024);
  // 3) small projections -> ln_a, scale_qk
  k_small_proj<<<2048, 256, 0, stream>>>(x, W_aang, b_aang, W_lnabs, b_lnabs, W_pscale, b_pscale, lnA, scaleq);
  // 4) A = cumsum(ln_a) per (b,h)
  k_cumsum<<<16, 1024, 0, stream>>>(lnA, A_buf);
  // 5) t -> qp, kp, v
  k_transform<<<2048, 256, 0, stream>>>(t_buf, scaleq, qp_buf, kp_buf, v_buf);
  // 6) per-chunk KV states
  k_chunkT<<<256, 256, 0, stream>>>(kp_buf, v_buf, A_buf, T_buf);
  // 7) chunk-state scan + hidden_next output (planar re/im)
  k_state_scan<<<16, 256, 0, stream>>>(hidden_r, hidden_i, A_buf, T_buf, S_buf, hid_re, hid_im, write_imag);
  // 8) per-chunk attention -> h (real layout [BL][H][128]) into hr_buf
  k_attn<<<256, 256, 0, stream>>>(qp_buf, kp_buf, v_buf, A_buf, S_buf, hr_buf);
  // 9) GroupNorm * silu(g), in place
  k_gn<<<2048, 256, 0, stream>>>(g_buf, hr_buf, gn_w, gn_b);
  // 10) y = hflat @ W_y^T + b_y -> 256 blocks
  k_gemm_mfma<64,128><<<dim3(1024/128, 2048/64), 256, 0, stream>>>(hr_buf, W_y, b_y, y_out, 2048, 1024, 1024);
}

// Round 5
// 311.308 us; speedup vs baseline: 1.3675x; 1.3675x over previous
//
#include <hip/hip_runtime.h>
#include <math.h>

// SioConvLayer fused forward, MI355X (r5).
// r4 PASSED at 425.7us; GEMMs were 397us, latency-bound (Occ 17%, MfmaUtil 11%).
// r5: pre-converted bf16 hi/lo operands + m97-style dbuf GEMM with
// global_load_lds(16B) + source-side XOR swizzle; fused QKV+G GEMM (512 blocks).
// Non-GEMM kernels byte-identical to r4 (validated), except k_gn now emits
// bf16 hi/lo planes for the y-GEMM.

#define LSEQ 1024
#define NCHUNK 16
#define CHK 64

typedef float2 cf;
typedef unsigned short u16;
typedef unsigned int u32;
typedef __bf16 b16x8 __attribute__((ext_vector_type(8)));
typedef float f32x4 __attribute__((ext_vector_type(4)));

__device__ __forceinline__ cf cmul(cf a, cf b){
  return make_float2(a.x*b.x - a.y*b.y, a.x*b.y + a.y*b.x);
}
__device__ __forceinline__ cf cfma(cf a, cf b, cf c){
  c.x = fmaf(a.x, b.x, fmaf(-a.y, b.y, c.x));
  c.y = fmaf(a.x, b.y, fmaf( a.y, b.x, c.y));
  return c;
}
__device__ __forceinline__ cf cexpf2(cf a){
  float e = expf(a.x); float s, c; sincosf(a.y, &s, &c);
  return make_float2(e*c, e*s);
}
__device__ __forceinline__ float p_angle_f(int h, int i){
  return expf(((float)(h*64+i)) * (1.0f/512.0f) * logf(1e-4f));
}

// ------------------- f32 -> bf16 hi/lo split (RNE both) ----------------------
__device__ __forceinline__ u16 bf16_rne(float f){
  u32 u = __float_as_uint(f);
  u += 0x7fffu + ((u >> 16) & 1u);
  return (u16)(u >> 16);
}
__device__ __forceinline__ void split_bf16(float f, u16& h, u16& l){
  u32 u = __float_as_uint(f);
  u32 r = (u + 0x7fffu + ((u >> 16) & 1u)) >> 16;
  h = (u16)r;
  float d = f - __uint_as_float(r << 16);
  l = bf16_rne(d);
}

// async 16B global->LDS (lds dest must be wave-uniform; HW adds lane*16)
__device__ __forceinline__ void gload_lds16(const u16* g, u16* l){
  __builtin_amdgcn_global_load_lds(
      (const __attribute__((address_space(1))) u32*)(const void*)g,
      (__attribute__((address_space(3))) u32*)(void*)l, 16, 0, 0);
}

// ---------------- conversion pass: f32[n] -> bf16 hi[n], lo[n] ---------------
__global__ __launch_bounds__(256) void k_convert(const float* __restrict__ in,
                                                 u16* __restrict__ hi,
                                                 u16* __restrict__ lo, int n){
  int i = (blockIdx.x*256 + threadIdx.x)*4;
  if (i >= n) return;
  float4 v = *(const float4*)(in + i);
  ushort4 h, l;
  split_bf16(v.x, h.x, l.x);
  split_bf16(v.y, h.y, l.y);
  split_bf16(v.z, h.z, l.z);
  split_bf16(v.w, h.w, l.w);
  *(ushort4*)(hi + i) = h;
  *(ushort4*)(lo + i) = l;
}

// ---------------- split-bf16 MFMA GEMM, dbuf + global_load_lds ---------------
// C[m,n] = sum_k A[m,k]*B[n,k] + bias[n], via A=Ah+Al, B=Bh+Bl (3 MFMAs).
// 256 threads = 4 waves (2x2); LDS tiles [rows][32] bf16 linear, 16B-slot
// swizzle slot' = slot ^ ((row>>1)&3) applied on the GLOBAL source (involution)
// and again on the ds_read address.
template<int BM, int BN>
__global__ __launch_bounds__(256, 2) void k_gemm_bs(
    const u16* __restrict__ Ahg, const u16* __restrict__ Alg,
    const u16* __restrict__ Bhg, const u16* __restrict__ Blg,
    const float* __restrict__ bias0, const float* __restrict__ bias1, int nsplit,
    float* __restrict__ C0, float* __restrict__ C1, int ldc0, int ldc1,
    int M, int N, int K){
  constexpr int MI = BM/32, NJ = BN/32;
  constexpr int NIA = BM/16, NIB = BN/16;        // gload issues per array
  constexpr int TOTIS = 2*NIA + 2*NIB;
  constexpr int LA = BM*32;                      // u16 per A array
  constexpr int LB = BN*32;
  __shared__ __align__(16) u16 lds[2][2*LA + 2*LB];
  int tid = threadIdx.x;
  int m0 = blockIdx.y * BM, n0 = blockIdx.x * BN;
  int wid = tid >> 6, lane = tid & 63;
  int wr = wid >> 1, wc = wid & 1;
  int fr = lane & 15, fq = lane >> 4;

  f32x4 acc[MI][NJ];
  #pragma unroll
  for (int mi = 0; mi < MI; mi++)
    #pragma unroll
    for (int nj = 0; nj < NJ; nj++)
      acc[mi][nj] = (f32x4){0.f, 0.f, 0.f, 0.f};

  int rlane = lane >> 2, slane = lane & 3;

  auto STAGE = [&](int buf, int k0){
    u16* L = &lds[buf][0];
    #pragma unroll
    for (int uu = 0; uu < TOTIS/4; uu++){
      int u = uu*4 + wid;
      int q; const u16* src; int lbase;
      if (u < NIA)            { q = u;              src = Ahg + (size_t)m0*K; lbase = 0; }
      else if (u < 2*NIA)     { q = u - NIA;        src = Alg + (size_t)m0*K; lbase = LA; }
      else if (u < 2*NIA+NIB) { q = u - 2*NIA;      src = Bhg + (size_t)n0*K; lbase = 2*LA; }
      else                    { q = u - 2*NIA-NIB;  src = Blg + (size_t)n0*K; lbase = 2*LA + LB; }
      int rl = q*16 + rlane;
      int colel = ((slane ^ ((rl>>1)&3)))*8;
      gload_lds16(src + (size_t)rl*K + k0 + colel, L + lbase + q*512);
    }
  };

  int NT = K/32;
  STAGE(0, 0);
  __syncthreads();
  int cur = 0;
  for (int t = 0; t < NT; t++){
    if (t+1 < NT) STAGE(cur^1, (t+1)*32);
    const u16* L = &lds[cur][0];
    b16x8 ah[MI], al[MI], bh[NJ], bl[NJ];
    #pragma unroll
    for (int mi = 0; mi < MI; mi++){
      int r = wr*(BM/2) + mi*16 + fr;
      int c = (fq ^ ((r>>1)&3))*8;
      ah[mi] = *(const b16x8*)(L + r*32 + c);
      al[mi] = *(const b16x8*)(L + LA + r*32 + c);
    }
    #pragma unroll
    for (int nj = 0; nj < NJ; nj++){
      int r = wc*(BN/2) + nj*16 + fr;
      int c = (fq ^ ((r>>1)&3))*8;
      bh[nj] = *(const b16x8*)(L + 2*LA + r*32 + c);
      bl[nj] = *(const b16x8*)(L + 2*LA + LB + r*32 + c);
    }
    #pragma unroll
    for (int mi = 0; mi < MI; mi++)
      #pragma unroll
      for (int nj = 0; nj < NJ; nj++){
        acc[mi][nj] = __builtin_amdgcn_mfma_f32_16x16x32_bf16(ah[mi], bh[nj], acc[mi][nj], 0, 0, 0);
        acc[mi][nj] = __builtin_amdgcn_mfma_f32_16x16x32_bf16(ah[mi], bl[nj], acc[mi][nj], 0, 0, 0);
        acc[mi][nj] = __builtin_amdgcn_mfma_f32_16x16x32_bf16(al[mi], bh[nj], acc[mi][nj], 0, 0, 0);
      }
    __syncthreads();
    cur ^= 1;
  }

  // C/D layout (validated r3/r4): col = lane&15, row = (lane>>4)*4 + reg
  int isC0 = (n0 < nsplit);
  float* Cp = isC0 ? C0 : C1;
  const float* bp = isC0 ? bias0 : bias1;
  int ld = isC0 ? ldc0 : ldc1;
  int nb = isC0 ? n0 : (n0 - nsplit);
  #pragma unroll
  for (int mi = 0; mi < MI; mi++)
    #pragma unroll
    for (int nj = 0; nj < NJ; nj++){
      int n = nb + wc*(BN/2) + nj*16 + fr;
      float bn = bp[n];
      #pragma unroll
      for (int r = 0; r < 4; r++){
        int m = m0 + wr*(BM/2) + mi*16 + fq*4 + r;
        Cp[(size_t)m*ld + n] = acc[mi][nj][r] + bn;
      }
    }
}

// ---------------- small projections: a_angle, ln_a_abs, scale_qk -------------
__global__ __launch_bounds__(256) void k_small_proj(
    const float* __restrict__ x,
    const float* __restrict__ W_aang, const float* __restrict__ b_aang,
    const float* __restrict__ W_lnabs, const float* __restrict__ b_lnabs,
    const float* __restrict__ W_pscale, const float* __restrict__ b_pscale,
    float* __restrict__ lnA, float* __restrict__ scaleq){
  int bl = blockIdx.x;
  int tid = threadIdx.x;
  const float* xr = x + (size_t)bl*1024;
  float part[24];
  #pragma unroll
  for (int r = 0; r < 24; r++) part[r] = 0.f;
  for (int k = tid; k < 1024; k += 256){
    float xv = xr[k];
    #pragma unroll
    for (int h = 0; h < 8; h++){
      part[h]    = fmaf(xv, W_aang  [h*1024+k], part[h]);
      part[8+h]  = fmaf(xv, W_lnabs [h*1024+k], part[8+h]);
      part[16+h] = fmaf(xv, W_pscale[h*1024+k], part[16+h]);
    }
  }
  __shared__ float red[24][4];
  int lane = tid & 63, wv = tid >> 6;
  #pragma unroll
  for (int r = 0; r < 24; r++){
    float s = part[r];
    #pragma unroll
    for (int off = 32; off >= 1; off >>= 1) s += __shfl_down(s, off);
    if (lane == 0) red[r][wv] = s;
  }
  __syncthreads();
  if (tid < 24){
    red[tid][0] = red[tid][0] + red[tid][1] + red[tid][2] + red[tid][3];
  }
  __syncthreads();
  if (tid < 8){
    int h = tid;
    float aang  = tanhf(red[h][0] + b_aang[h]);
    float lnabs = -expf(red[8+h][0] + b_lnabs[h]);
    float scv   = red[16+h][0] + b_pscale[h];
    float sc    = -1.f / (1.f + expf(-scv));
    float pa0   = p_angle_f(h, 0);
    lnA[(bl*8+h)*2+0] = lnabs * pa0;
    lnA[(bl*8+h)*2+1] = aang  * pa0;
    scaleq[bl*8+h] = sc;
  }
}

// ---------------- inclusive cumsum of ln_a over L per (b,h) ------------------
__global__ void k_cumsum(const float* __restrict__ lnA, float* __restrict__ Aout){
  int bh = blockIdx.x; int b = bh >> 3, h = bh & 7;
  __shared__ float2 buf[2][LSEQ];
  int l = threadIdx.x;
  float2 v;
  v.x = lnA[(((size_t)b*LSEQ + l)*8 + h)*2 + 0];
  v.y = lnA[(((size_t)b*LSEQ + l)*8 + h)*2 + 1];
  buf[0][l] = v;
  __syncthreads();
  int src = 0;
  for (int off = 1; off < LSEQ; off <<= 1){
    float2 w = buf[src][l];
    if (l >= off){ float2 u = buf[src][l-off]; w.x += u.x; w.y += u.y; }
    buf[src^1][l] = w;
    __syncthreads();
    src ^= 1;
  }
  float2 r = buf[src][l];
  ((float2*)Aout)[(size_t)bh*LSEQ + l] = r;
}

// ---------------- t -> qp, kp, v ([BH][L][I] float2) -------------------------
__global__ __launch_bounds__(256) void k_transform(
    const float* __restrict__ t, const float* __restrict__ scaleq,
    float* __restrict__ qp, float* __restrict__ kp, float* __restrict__ v){
  int bl = blockIdx.x; int b = bl >> 10, l = bl & 1023;
  int tid = threadIdx.x;
  const float* tr = t + (size_t)bl*3072;
  float lnSc = logf(1024.f) - logf(32.f);
  for (int p = tid; p < 512; p += 256){
    int h = p >> 6, i = p & 63;
    const float2* tf = (const float2*)(tr + h*384 + i*6);
    float2 q  = tf[0];
    float2 kk = tf[1];
    float2 vv = tf[2];
    float sq_ = 1.f/(1.f + sqrtf(q.x*q.x + q.y*q.y));   q.x*=sq_; q.y*=sq_;
    float sk_ = 1.f/(1.f + sqrtf(kk.x*kk.x + kk.y*kk.y)); kk.x*=sk_; kk.y*=sk_;
    float sv_ = 1.f/(1.f + sqrtf(vv.x*vv.x + vv.y*vv.y)); vv.x*=sv_; vv.y*=sv_;
    float pa  = p_angle_f(h, i);
    float pas = expf(logf(32.f) + ((float)h)*(1.f/7.f)*lnSc);
    float sc  = scaleq[bl*8+h];
    float diff = sc * pas * pa;
    float phase = pa * (float)l;
    float aq, ak;
    if ((i & 1) == 0){ aq = phase + diff; ak = -phase; }
    else             { aq = phase;        ak = -phase + diff; }
    float s1, c1; sincosf(aq, &s1, &c1);
    float s2, c2; sincosf(ak, &s2, &c2);
    float2 qpv = cmul(q,  make_float2(c1, s1));
    float2 kpv = cmul(kk, make_float2(c2, s2));
    size_t idx = (((size_t)(b*8+h))*LSEQ + l)*64 + i;
    ((float2*)qp)[idx] = qpv;
    ((float2*)kp)[idx] = kpv;
    ((float2*)v )[idx] = vv;
  }
}

// ---------------- per-chunk KV state T_c (stored transposed [j][i]) ----------
__global__ __launch_bounds__(256) void k_chunkT(
    const float* __restrict__ kp, const float* __restrict__ v,
    const float* __restrict__ A, float* __restrict__ T){
  int blk = blockIdx.x;
  int bh = blk >> 4, c = blk & 15;
  int l0 = c*CHK;
  __shared__ float2 kpS[64][65];
  __shared__ float2 vS [64][65];
  __shared__ float2 wS [64];
  int tid = threadIdx.x;
  const float2* kpg = (const float2*)kp + ((size_t)bh*LSEQ + l0)*64;
  const float2* vg  = (const float2*)v  + ((size_t)bh*LSEQ + l0)*64;
  for (int e = tid; e < 4096; e += 256){
    kpS[e>>6][e&63] = kpg[e];
    vS [e>>6][e&63] = vg [e];
  }
  const float2* Ag = (const float2*)A + (size_t)bh*LSEQ;
  if (tid < 64){
    float2 Aend = Ag[l0+63];
    float2 Am   = Ag[l0+tid];
    wS[tid] = cexpf2(make_float2(Aend.x - Am.x, Aend.y - Am.y));
  }
  __syncthreads();
  int i = tid & 63, jg = tid >> 6;
  float2 acc[16];
  #pragma unroll
  for (int jj = 0; jj < 16; jj++) acc[jj] = make_float2(0.f, 0.f);
  for (int m = 0; m < 64; m++){
    float2 wkp = cmul(wS[m], kpS[m][i]);
    #pragma unroll
    for (int jj = 0; jj < 16; jj++)
      acc[jj] = cfma(wkp, vS[m][jg*16+jj], acc[jj]);
  }
  float2* Tg = (float2*)T + (size_t)blk*4096;
  #pragma unroll
  for (int jj = 0; jj < 16; jj++)
    Tg[(jg*16+jj)*64 + i] = acc[jj];
}

// ---------------- sequential chunk-state scan + hidden_next (planar) ---------
__global__ __launch_bounds__(256) void k_state_scan(
    const float* __restrict__ hidden_r, const float* __restrict__ hidden_i,
    const float* __restrict__ A, const float* __restrict__ T,
    float* __restrict__ S_states, float* __restrict__ out_re,
    float* __restrict__ out_im, int write_imag){
  int bh = blockIdx.x; int h = bh & 7;
  int tid = threadIdx.x;
  float2 S[16];
  #pragma unroll
  for (int t = 0; t < 16; t++){
    int e = tid + 256*t;
    int j = e >> 6, i = e & 63;
    float pa = p_angle_f(h, i);
    float hr = hidden_r[(size_t)bh*4096 + i*64 + j];
    float hi = hidden_i[(size_t)bh*4096 + i*64 + j];
    float sn, cs; sincosf(pa, &sn, &cs);
    S[t] = cmul(make_float2(hr, hi), make_float2(cs, sn));
  }
  const float2* Ag = (const float2*)A + (size_t)bh*LSEQ;
  for (int c = 0; c < NCHUNK; c++){
    #pragma unroll
    for (int t = 0; t < 16; t++)
      ((float2*)S_states)[((size_t)bh*16 + c)*4096 + tid + 256*t] = S[t];
    float2 Aend  = Ag[c*CHK + 63];
    float2 Aprev = (c > 0) ? Ag[c*CHK - 1] : make_float2(0.f, 0.f);
    float2 P = cexpf2(make_float2(Aend.x - Aprev.x, Aend.y - Aprev.y));
    const float2* Tg = (const float2*)T + ((size_t)bh*16 + c)*4096;
    #pragma unroll
    for (int t = 0; t < 16; t++){
      float2 Tv = Tg[tid + 256*t];
      float2 Sn = cmul(P, S[t]);
      S[t] = make_float2(Sn.x + Tv.x, Sn.y + Tv.y);
    }
  }
  #pragma unroll
  for (int t = 0; t < 16; t++){
    int e = tid + 256*t;
    int j = e >> 6, i = e & 63;
    float pa = p_angle_f(h, i);
    float sn, cs; sincosf(pa * (float)(LSEQ-1), &sn, &cs);
    float2 r = cmul(S[t], make_float2(cs, sn));
    size_t o = (size_t)bh*4096 + i*64 + j;
    out_re[o] = r.x;
    if (write_imag) out_im[o] = r.y;
  }
}

// ---------------- per-chunk attention: intra-quadratic + cross-state ---------
__global__ __launch_bounds__(256) void k_attn(
    const float* __restrict__ qp, const float* __restrict__ kp,
    const float* __restrict__ v, const float* __restrict__ A,
    const float* __restrict__ S_states, float* __restrict__ hr_out){
  int blk = blockIdx.x;
  int bh = blk >> 4, c = blk & 15;
  int b = bh >> 3, h = bh & 7;
  int l0 = c*CHK;
  __shared__ float2 bufQ[64][65];
  __shared__ float2 bufK[64][65];
  __shared__ float2 bufC[64][65];
  __shared__ float2 dA[64];
  __shared__ float2 eD[64];
  int tid = threadIdx.x;
  const float2* qpg = (const float2*)qp + ((size_t)bh*LSEQ + l0)*64;
  const float2* kpg = (const float2*)kp + ((size_t)bh*LSEQ + l0)*64;
  for (int e = tid; e < 4096; e += 256){
    bufQ[e>>6][e&63] = qpg[e];
    bufK[e>>6][e&63] = kpg[e];
  }
  const float2* Ag = (const float2*)A + (size_t)bh*LSEQ;
  if (tid < 64){
    float2 As = (l0 > 0) ? Ag[l0-1] : make_float2(0.f, 0.f);
    float2 Al = Ag[l0+tid];
    float2 d = make_float2(Al.x - As.x, Al.y - As.y);
    dA[tid] = d;
    eD[tid] = cexpf2(d);
  }
  __syncthreads();
  {
    int l = tid >> 2, mg = tid & 3;
    float2 acc[16];
    #pragma unroll
    for (int mm = 0; mm < 16; mm++) acc[mm] = make_float2(0.f, 0.f);
    for (int i = 0; i < 64; i++){
      float2 qv = bufQ[l][i];
      #pragma unroll
      for (int mm = 0; mm < 16; mm++)
        acc[mm] = cfma(qv, bufK[mg + 4*mm][i], acc[mm]);
    }
    float2 dl = dA[l];
    #pragma unroll
    for (int mm = 0; mm < 16; mm++){
      int m = mg + 4*mm;
      float2 w = make_float2(0.f, 0.f);
      if (m <= l){
        float2 dm = dA[m];
        w = cexpf2(make_float2(dl.x - dm.x, dl.y - dm.y));
      }
      bufC[l][m] = cmul(acc[mm], w);
    }
  }
  __syncthreads();
  for (int e = tid; e < 4096; e += 256){
    int l = e >> 6, i = e & 63;
    bufQ[l][i] = cmul(bufQ[l][i], eD[l]);
  }
  const float2* Sg = (const float2*)S_states + (size_t)blk*4096;
  for (int e = tid; e < 4096; e += 256)
    bufK[e>>6][e&63] = Sg[e];
  __syncthreads();
  int l = tid >> 2, jg = tid & 3;
  float2 hacc[16];
  #pragma unroll
  for (int jj = 0; jj < 16; jj++) hacc[jj] = make_float2(0.f, 0.f);
  for (int i = 0; i < 64; i++){
    float2 qw = bufQ[l][i];
    #pragma unroll
    for (int jj = 0; jj < 16; jj++)
      hacc[jj] = cfma(qw, bufK[jg + 4*jj][i], hacc[jj]);
  }
  __syncthreads();
  const float2* vg = (const float2*)v + ((size_t)bh*LSEQ + l0)*64;
  for (int e = tid; e < 4096; e += 256)
    bufQ[e>>6][e&63] = vg[e];
  __syncthreads();
  for (int m = 0; m < 64; m++){
    float2 qc = bufC[l][m];
    #pragma unroll
    for (int jj = 0; jj < 16; jj++)
      hacc[jj] = cfma(qc, bufQ[m][jg + 4*jj], hacc[jj]);
  }
  float2* out = (float2*)hr_out;
  size_t base = (((size_t)(b*LSEQ + l0 + l))*8 + h)*64;
  #pragma unroll
  for (int jj = 0; jj < 16; jj++)
    out[base + jg + 4*jj] = hacc[jj];
}

// -------- GroupNorm * silu(g) -> bf16 hi/lo planes (fused conversion) --------
__global__ __launch_bounds__(256) void k_gn(
    const float* __restrict__ g, const float* __restrict__ hr,
    const float* __restrict__ gn_w, const float* __restrict__ gn_b,
    u16* __restrict__ hnh, u16* __restrict__ hnl){
  int bl = blockIdx.x;
  int tid = threadIdx.x;
  int h = tid >> 5, c32 = tid & 31;
  const float* hp = hr + ((size_t)bl*8 + h)*128 + c32*4;
  const float* gp = g + (size_t)bl*1024 + h*128 + c32*4;
  float4 v = *(const float4*)hp;
  float s = v.x + v.y + v.z + v.w;
  #pragma unroll
  for (int off = 16; off >= 1; off >>= 1) s += __shfl_xor(s, off);
  float mean = s * (1.f/128.f);
  float dx = v.x - mean, dy = v.y - mean, dz = v.z - mean, dw = v.w - mean;
  float ss = dx*dx + dy*dy + dz*dz + dw*dw;
  #pragma unroll
  for (int off = 16; off >= 1; off >>= 1) ss += __shfl_xor(ss, off);
  float inv = rsqrtf(ss * (1.f/128.f) + 1e-5f);
  float w = gn_w[h] * inv, bb = gn_b[h];
  float4 gv = *(const float4*)gp;
  float4 o;
  o.x = (dx*w + bb) * (gv.x / (1.f + expf(-gv.x)));
  o.y = (dy*w + bb) * (gv.y / (1.f + expf(-gv.y)));
  o.z = (dz*w + bb) * (gv.z / (1.f + expf(-gv.z)));
  o.w = (dw*w + bb) * (gv.w / (1.f + expf(-gv.w)));
  ushort4 oh, ol;
  split_bf16(o.x, oh.x, ol.x);
  split_bf16(o.y, oh.y, ol.y);
  split_bf16(o.z, oh.z, ol.z);
  split_bf16(o.w, oh.w, ol.w);
  size_t idx = (size_t)bl*1024 + h*128 + c32*4;
  *(ushort4*)(hnh + idx) = oh;
  *(ushort4*)(hnl + idx) = ol;
}

extern "C" void kernel_launch(void* const* d_in, const int* in_sizes, int n_in,
                              void* d_out, int out_size, void* d_ws, size_t ws_size,
                              hipStream_t stream) {
  const float* x        = (const float*)d_in[0];
  const float* hidden_r = (const float*)d_in[1];
  const float* hidden_i = (const float*)d_in[2];
  const float* W_qkv    = (const float*)d_in[3];
  const float* b_qkv    = (const float*)d_in[4];
  const float* W_g      = (const float*)d_in[5];
  const float* b_g      = (const float*)d_in[6];
  const float* W_aang   = (const float*)d_in[7];
  const float* b_aang   = (const float*)d_in[8];
  const float* W_lnabs  = (const float*)d_in[9];
  const float* b_lnabs  = (const float*)d_in[10];
  const float* W_pscale = (const float*)d_in[11];
  const float* b_pscale = (const float*)d_in[12];
  const float* W_y      = (const float*)d_in[13];
  const float* b_y      = (const float*)d_in[14];
  const float* gn_w     = (const float*)d_in[15];
  const float* gn_b     = (const float*)d_in[16];

  float* ws = (float*)d_ws;
  // R0 [0, 6,291,456): t_buf; later hr [0,2M), hn hi/lo [2M,4M) (old T), S [4M,6M)
  float* t_buf  = ws;
  float* hr_buf = t_buf;
  float* T_buf  = t_buf + 2097152;
  float* S_buf  = t_buf + 4194304;
  u16*   hnh    = (u16*)(t_buf + 2097152);          // overlays T (dead by then)
  u16*   hnl    = (u16*)(t_buf + 2097152) + 2097152;
  // R1
  float* g_buf  = ws + 6291456;                     // 2,097,152
  // R2 [8,388,608, 12,582,912): Wch+Wcl; later qp, kp
  u16*   Wch    = (u16*)(ws + 8388608);             // 4096*1024 u16
  u16*   Wcl    = Wch + 4194304;
  float* qp_buf = ws + 8388608;
  float* kp_buf = ws + 10485760;
  // R3 [12,582,912, 14,680,064): xh+xl; later v
  u16*   xh     = (u16*)(ws + 12582912);            // 2048*1024 u16
  u16*   xl     = xh + 2097152;
  float* v_buf  = ws + 12582912;
  // R4
  u16*   Wyh    = (u16*)(ws + 14680064);            // 1024*1024 u16
  u16*   Wyl    = Wyh + 1048576;
  // R5
  float* lnA    = ws + 15728640;                    // 32,768
  float* scaleq = lnA + 32768;                      // 16,384
  float* A_buf  = scaleq + 16384;                   // 32,768
  // total 15,810,560 f32 = 63.2 MB

  float* y_out  = (float*)d_out;
  float* hid_re = (float*)d_out + 2097152;
  float* hid_im = (float*)d_out + 2097152 + 65536;
  int write_imag = (out_size >= 2097152 + 2*65536) ? 1 : 0;

  // 0) conversions: x, [W_qkv;W_g] concat, W_y -> bf16 hi/lo
  k_convert<<<2048, 256, 0, stream>>>(x, xh, xl, 2097152);
  k_convert<<<3072, 256, 0, stream>>>(W_qkv, Wch, Wcl, 3145728);
  k_convert<<<1024, 256, 0, stream>>>(W_g, Wch + 3145728, Wcl + 3145728, 1048576);
  k_convert<<<1024, 256, 0, stream>>>(W_y, Wyh, Wyl, 1048576);

  // 1) fused [t|g] = x @ [W_qkv;W_g]^T + bias   (M=2048, N=4096) -> 512 blocks
  k_gemm_bs<128,128><<<dim3(4096/128, 2048/128), 256, 0, stream>>>(
      xh, xl, Wch, Wcl, b_qkv, b_g, 3072, t_buf, g_buf, 3072, 1024, 2048, 4096, 1024);
  // 2) small projections -> ln_a, scale_qk
  k_small_proj<<<2048, 256, 0, stream>>>(x, W_aang, b_aang, W_lnabs, b_lnabs, W_pscale, b_pscale, lnA, scaleq);
  // 3) A = cumsum(ln_a)
  k_cumsum<<<16, 1024, 0, stream>>>(lnA, A_buf);
  // 4) t -> qp, kp, v   (qp/kp overlay Wc region, v overlays xh/xl: both dead)
  k_transform<<<2048, 256, 0, stream>>>(t_buf, scaleq, qp_buf, kp_buf, v_buf);
  // 5) per-chunk KV states
  k_chunkT<<<256, 256, 0, stream>>>(kp_buf, v_buf, A_buf, T_buf);
  // 6) chunk-state scan + hidden_next (planar)
  k_state_scan<<<16, 256, 0, stream>>>(hidden_r, hidden_i, A_buf, T_buf, S_buf, hid_re, hid_im, write_imag);
  // 7) per-chunk attention -> hr
  k_attn<<<256, 256, 0, stream>>>(qp_buf, kp_buf, v_buf, A_buf, S_buf, hr_buf);
  // 8) GroupNorm * silu(g) -> bf16 hi/lo (overlays dead T region)
  k_gn<<<2048, 256, 0, stream>>>(g_buf, hr_buf, gn_w, gn_b, hnh, hnl);
  // 9) y = hn @ W_y^T + b_y   (M=2048, N=1024) -> 512 blocks
  k_gemm_bs<64,64><<<dim3(1024/64, 2048/64), 256, 0, stream>>>(
      hnh, hnl, Wyh, Wyl, b_y, b_y, 1024, y_out, y_out, 1024, 1024, 2048, 1024, 1024);
}